// Round 1
// baseline (446.648 us; speedup 1.0000x reference)
//
#include <hip/hip_runtime.h>

typedef _Float16 f16;
typedef _Float16 f16x4 __attribute__((ext_vector_type(4)));
typedef _Float16 f16x8 __attribute__((ext_vector_type(8)));
typedef float    f32x4 __attribute__((ext_vector_type(4)));

#define NROWS 65536
#define DDIM  512
#define BM 128
#define BN 128
#define BK 32
#define PAD 8           // f16 pad -> row stride 40 f16 = 80 B (2-way-max bank aliasing, free)

// ---------------------------------------------------------------------------
// K0: W [k][n] fp32 row-major  ->  Wt [n][k] f16  (so GEMM B-staging is
// k-contiguous, matching the MFMA B-fragment layout B[k=quad*8+j][n=lane&15]).
// ---------------------------------------------------------------------------
__global__ __launch_bounds__(1024) void k_transpose(const float* __restrict__ W,
                                                    f16* __restrict__ Wt) {
  __shared__ float t[32][33];
  const int tx = threadIdx.x, ty = threadIdx.y;
  const int n0 = blockIdx.x * 32, k0 = blockIdx.y * 32;
  t[ty][tx] = W[(size_t)(k0 + ty) * DDIM + n0 + tx];
  __syncthreads();
  Wt[(size_t)(n0 + ty) * DDIM + k0 + tx] = (f16)t[tx][ty];
}

// ---------------------------------------------------------------------------
// K1: feature = inputs @ W  (f16 MFMA, fp32 acc), fused ghost-BN + priors.
// One block = 128 rows (exactly one ghost batch) x 128 cols -> column stats
// are complete within the block. Writes z = ((x-mu)*rstd*gamma+beta)*prior
// as fp32 into Z (= d_out; sparsemax kernel then runs in-place).
// ---------------------------------------------------------------------------
__global__ __launch_bounds__(256) void k_gemm_bn(const float* __restrict__ A,
                                                 const float* __restrict__ priors,
                                                 const f16*  __restrict__ Bt,
                                                 const float* __restrict__ gamma,
                                                 const float* __restrict__ beta,
                                                 float* __restrict__ Z) {
  __shared__ __align__(16) f16 Al[BM][BK + PAD];
  __shared__ __align__(16) f16 Bl[BN][BK + PAD];
  __shared__ float2 part[2][BN];   // per-wm-half (sum, sumsq) partials per column
  __shared__ float2 sb[BN];        // per-column (scale, shift)

  const int m0 = blockIdx.y * BM;          // ghost-batch row base
  const int c0 = blockIdx.x * BN;          // column base
  const int tid  = threadIdx.x;
  const int lane = tid & 63;
  const int wid  = tid >> 6;               // 0..3
  const int wm = wid >> 1, wn = wid & 1;   // 2x2 wave grid, wave tile 64x64
  const int lr = lane & 15;                // A-row / B-col / C-col selector
  const int lq = lane >> 4;                // quad

  f32x4 acc[4][4];
#pragma unroll
  for (int i = 0; i < 4; ++i)
#pragma unroll
    for (int j = 0; j < 4; ++j) acc[i][j] = (f32x4){0.f, 0.f, 0.f, 0.f};

  for (int ks = 0; ks < DDIM / BK; ++ks) {
    const int kb = ks * BK;
    // --- stage A tile (fp32 -> f16): 128x32 = 1024 float4, 4 per thread ---
#pragma unroll
    for (int t = 0; t < 4; ++t) {
      const int f4  = tid + t * 256;       // 0..1023
      const int row = f4 >> 3;             // 8 float4 per row
      const int kk  = (f4 & 7) << 2;
      const float4 v = *(const float4*)(A + (size_t)(m0 + row) * DDIM + kb + kk);
      f16x4 h = {(f16)v.x, (f16)v.y, (f16)v.z, (f16)v.w};
      *(f16x4*)(&Al[row][kk]) = h;
    }
    // --- stage B tile (f16 direct): 128x32 = 512 f16x8, 2 per thread ---
#pragma unroll
    for (int t = 0; t < 2; ++t) {
      const int f8 = tid + t * 256;        // 0..511
      const int n  = f8 >> 2;              // 4 f16x8 per row
      const int kk = (f8 & 3) << 3;
      f16x8 v = *(const f16x8*)(Bt + (size_t)(c0 + n) * DDIM + kb + kk);
      *(f16x8*)(&Bl[n][kk]) = v;
    }
    __syncthreads();
    // --- MFMA: wave tile 64x64 = 4x4 tiles of 16x16, K=32 in one step ---
    f16x8 af[4], bf[4];
#pragma unroll
    for (int mi = 0; mi < 4; ++mi)
      af[mi] = *(const f16x8*)(&Al[wm * 64 + mi * 16 + lr][lq * 8]);
#pragma unroll
    for (int ni = 0; ni < 4; ++ni)
      bf[ni] = *(const f16x8*)(&Bl[wn * 64 + ni * 16 + lr][lq * 8]);
#pragma unroll
    for (int mi = 0; mi < 4; ++mi)
#pragma unroll
      for (int ni = 0; ni < 4; ++ni)
        acc[mi][ni] = __builtin_amdgcn_mfma_f32_16x16x32_f16(af[mi], bf[ni], acc[mi][ni], 0, 0, 0);
    __syncthreads();
  }

  // --- ghost-BN stats: column sums over the block's 128 rows ---
  // C/D layout: col = lane&15, row = lq*4 + r  (within each 16x16 tile)
#pragma unroll
  for (int ni = 0; ni < 4; ++ni) {
    float ps = 0.f, pq = 0.f;
#pragma unroll
    for (int mi = 0; mi < 4; ++mi)
#pragma unroll
      for (int r = 0; r < 4; ++r) {
        const float v = acc[mi][ni][r];
        ps += v; pq += v * v;
      }
    ps += __shfl_xor(ps, 16); ps += __shfl_xor(ps, 32);
    pq += __shfl_xor(pq, 16); pq += __shfl_xor(pq, 32);
    if (lq == 0) part[wm][wn * 64 + ni * 16 + lr] = make_float2(ps, pq);
  }
  __syncthreads();
  if (tid < BN) {
    const int c = tid;
    const float sum = part[0][c].x + part[1][c].x;
    const float ssq = part[0][c].y + part[1][c].y;
    const float mean = sum * (1.f / 128.f);
    const float var  = ssq * (1.f / 128.f) - mean * mean;
    const float rstd = rsqrtf(var + 1e-3f);
    const float s = rstd * gamma[c0 + c];
    const float b = beta[c0 + c] - mean * s;
    sb[c] = make_float2(s, b);
  }
  __syncthreads();

  // --- apply BN + priors, write z (fp32) ---
#pragma unroll
  for (int ni = 0; ni < 4; ++ni) {
    const int c = wn * 64 + ni * 16 + lr;
    const float2 s_b = sb[c];
#pragma unroll
    for (int mi = 0; mi < 4; ++mi)
#pragma unroll
      for (int r = 0; r < 4; ++r) {
        const int row = wm * 64 + mi * 16 + lq * 4 + r;
        const size_t off = (size_t)(m0 + row) * DDIM + c0 + c;
        const float z = acc[mi][ni][r] * s_b.x + s_b.y;
        Z[off] = z * priors[off];
      }
  }
}

// ---------------------------------------------------------------------------
// K2: sparsemax per row, in place on Z. One wave per row: 512 values = 8/lane.
// Michelot fixed-point: tau = (sum_{z>tau} z - 1)/|{z>tau}|; support shrinks
// monotonically; converged when |support| stops changing (exact projection).
// ---------------------------------------------------------------------------
__device__ __forceinline__ float wave_sum(float v) {
  v += __shfl_xor(v, 1);  v += __shfl_xor(v, 2);  v += __shfl_xor(v, 4);
  v += __shfl_xor(v, 8);  v += __shfl_xor(v, 16); v += __shfl_xor(v, 32);
  return v;
}

__global__ __launch_bounds__(256) void k_sparsemax(float* __restrict__ Z) {
  const int lane = threadIdx.x & 63;
  const int wid  = threadIdx.x >> 6;
  const int row  = blockIdx.x * 4 + wid;
  float* zr = Z + (size_t)row * DDIM + lane * 8;

  float z[8];
  {
    const float4 v0 = *(const float4*)(zr);
    const float4 v1 = *(const float4*)(zr + 4);
    z[0] = v0.x; z[1] = v0.y; z[2] = v0.z; z[3] = v0.w;
    z[4] = v1.x; z[5] = v1.y; z[6] = v1.z; z[7] = v1.w;
  }

  float ps = z[0] + z[1] + z[2] + z[3] + z[4] + z[5] + z[6] + z[7];
  float tau = (wave_sum(ps) - 1.f) * (1.f / 512.f);

  int kprev = 512;
  for (int it = 0; it < 512; ++it) {
    float s = 0.f, cnt = 0.f;
#pragma unroll
    for (int j = 0; j < 8; ++j) {
      const bool a = z[j] > tau;
      s   += a ? z[j] : 0.f;
      cnt += a ? 1.f : 0.f;
    }
    s   = wave_sum(s);
    cnt = wave_sum(cnt);
    const int k = (int)cnt;
    tau = (s - 1.f) / cnt;
    if (k == kprev) break;   // support stable -> exact fixed point
    kprev = k;
  }

  float4 o0, o1;
  o0.x = fmaxf(z[0] - tau, 0.f); o0.y = fmaxf(z[1] - tau, 0.f);
  o0.z = fmaxf(z[2] - tau, 0.f); o0.w = fmaxf(z[3] - tau, 0.f);
  o1.x = fmaxf(z[4] - tau, 0.f); o1.y = fmaxf(z[5] - tau, 0.f);
  o1.z = fmaxf(z[6] - tau, 0.f); o1.w = fmaxf(z[7] - tau, 0.f);
  *(float4*)(zr)     = o0;
  *(float4*)(zr + 4) = o1;
}

// ---------------------------------------------------------------------------
extern "C" void kernel_launch(void* const* d_in, const int* in_sizes, int n_in,
                              void* d_out, int out_size, void* d_ws, size_t ws_size,
                              hipStream_t stream) {
  const float* inputs = (const float*)d_in[0];
  const float* priors = (const float*)d_in[1];
  const float* W      = (const float*)d_in[2];
  const float* gamma  = (const float*)d_in[3];
  const float* beta   = (const float*)d_in[4];
  float* out = (float*)d_out;
  f16*   Wt  = (f16*)d_ws;   // 512*512*2 B = 512 KB scratch

  hipLaunchKernelGGL(k_transpose, dim3(DDIM / 32, DDIM / 32), dim3(32, 32), 0, stream, W, Wt);
  hipLaunchKernelGGL(k_gemm_bn, dim3(DDIM / BN, NROWS / BM), dim3(256), 0, stream,
                     inputs, priors, Wt, gamma, beta, out);
  hipLaunchKernelGGL(k_sparsemax, dim3(NROWS / 4), dim3(256), 0, stream, out);
}